// Round 1
// baseline (160.063 us; speedup 1.0000x reference)
//
#include <hip/hip_runtime.h>
#include <math.h>

#define Bb 8
#define Cc 64
#define Nn 256
#define FD 128

// ---------------------------------------------------------------------------
// k1: one block per (b,c) pair. Computes:
//   - row logits dot_n = <h[n,:], op[c][FD:]> + <src, op[c][:FD]>  (mask = dot>=0)
//   - supp/query column sums -> supp_attn / query_attn -> 2-way softmax (w_s,w_q)
//   - per-row weight w[n] = mask ? w_s : w_q   (written to ws)
//   - channel partial sums:  S = sum_n w*rowsum,  SS = sum_n w^2*rowsumsq
// ---------------------------------------------------------------------------
__global__ __launch_bounds__(256) void k1(
    const float* __restrict__ h, const float* __restrict__ op,
    const float* __restrict__ opS, const float* __restrict__ opQ,
    float* __restrict__ w_out, float* __restrict__ partials) {
  const int bc = blockIdx.x;
  const int c = bc & (Cc - 1);
  const float* __restrict__ tile = h + (size_t)bc * (Nn * FD);

  __shared__ float s_ops[FD];      // op[c][0:FD]   (source half)
  __shared__ float s_oph[FD];      // op[c][FD:2FD] (h half)
  __shared__ float s_dot[Nn];
  __shared__ float s_rs[Nn];
  __shared__ float s_rss[Nn];
  __shared__ float s_acc_s[8][FD];
  __shared__ float s_acc_q[8][FD];
  __shared__ float s_supp[FD];
  __shared__ float s_query[FD];
  __shared__ float s_scalar[8];
  __shared__ float s_wp[8];

  const int tid = threadIdx.x;
  const int lane = tid & 63;
  const int wv = tid >> 6;

  const float* __restrict__ opc  = op  + c * (2 * FD);
  const float* __restrict__ opSc = opS + c * (2 * FD);
  const float* __restrict__ opQc = opQ + c * (2 * FD);

  if (tid < FD) {
    s_ops[tid] = opc[tid];
    s_oph[tid] = opc[FD + tid];
  }
  __syncthreads();

  // ---- wave 0: the three source dots (const_src, srcS, srcQ) ----
  if (wv == 0) {
    float a = tile[lane], b2 = tile[lane + 64];   // source row = n=0
    float cs = a * s_ops[lane] + b2 * s_ops[lane + 64];
    float ss = a * opSc[FD + lane] + b2 * opSc[FD + lane + 64];
    float qq = a * opQc[FD + lane] + b2 * opQc[FD + lane + 64];
#pragma unroll
    for (int off = 32; off >= 1; off >>= 1) {
      cs += __shfl_xor(cs, off, 64);
      ss += __shfl_xor(ss, off, 64);
      qq += __shfl_xor(qq, off, 64);
    }
    if (lane == 0) { s_scalar[0] = cs; s_scalar[1] = ss; s_scalar[2] = qq; }
  }
  __syncthreads();
  const float const_src = s_scalar[0];

  // ---- Pass A: per-row dot / rowsum / rowsumsq (half-wave per row, float4) ----
  {
    const int hl = lane & 31;      // half-lane
    const int rsel = lane >> 5;    // row select within pair
    const float4 o4 = ((const float4*)s_oph)[hl];
#pragma unroll 4
    for (int i = 0; i < 32; ++i) {
      int n = wv * 64 + 2 * i + rsel;
      float4 v = ((const float4*)(tile + n * FD))[hl];
      float d   = v.x * o4.x + v.y * o4.y + v.z * o4.z + v.w * o4.w;
      float rs  = v.x + v.y + v.z + v.w;
      float rss = v.x * v.x + v.y * v.y + v.z * v.z + v.w * v.w;
#pragma unroll
      for (int off = 16; off >= 1; off >>= 1) {
        d   += __shfl_xor(d, off, 64);
        rs  += __shfl_xor(rs, off, 64);
        rss += __shfl_xor(rss, off, 64);
      }
      if (hl == 0) { s_dot[n] = d + const_src; s_rs[n] = rs; s_rss[n] = rss; }
    }
  }
  __syncthreads();

  // ---- Pass B: column sums for supp / query (float4, coalesced rows) ----
  {
    const int f4  = tid & 31;        // float4 index within row
    const int sub = (tid >> 5) & 3;  // row offset within group of 4
    const int g   = tid >> 7;        // n-half
    const int slot = g * 4 + sub;
    float4 ssum = {0, 0, 0, 0}, qsum = {0, 0, 0, 0};
#pragma unroll 4
    for (int it = 0; it < 32; ++it) {
      int n = g * 128 + it * 4 + sub;
      float4 v = ((const float4*)(tile + n * FD))[f4];
      if (s_dot[n] >= 0.0f) {
        ssum.x += v.x; ssum.y += v.y; ssum.z += v.z; ssum.w += v.w;
      } else {
        qsum.x += v.x; qsum.y += v.y; qsum.z += v.z; qsum.w += v.w;
      }
    }
    ((float4*)s_acc_s[slot])[f4] = ssum;
    ((float4*)s_acc_q[slot])[f4] = qsum;
  }
  __syncthreads();
  if (tid < FD) {
    float v = 0;
#pragma unroll
    for (int k = 0; k < 8; ++k) v += s_acc_s[k][tid];
    s_supp[tid] = v;
  } else {
    int f = tid - FD;
    float v = 0;
#pragma unroll
    for (int k = 0; k < 8; ++k) v += s_acc_q[k][f];
    s_query[f] = v;
  }
  __syncthreads();

  // ---- wave 0: supp/query attn scalars + 2-way softmax ----
  if (wv == 0) {
    float sa = s_supp[lane] * opSc[lane] + s_supp[lane + 64] * opSc[lane + 64];
    float qa = s_query[lane] * opQc[lane] + s_query[lane + 64] * opQc[lane + 64];
#pragma unroll
    for (int off = 32; off >= 1; off >>= 1) {
      sa += __shfl_xor(sa, off, 64);
      qa += __shfl_xor(qa, off, 64);
    }
    if (lane == 0) {
      sa = sa * (1.0f / Nn) + s_scalar[1];   // mean over n, + source term
      qa = qa * (1.0f / Nn) + s_scalar[2];
      float mx = fmaxf(sa, qa);
      float es = expf(sa - mx), eq = expf(qa - mx);
      float inv = 1.0f / (es + eq);
      s_scalar[3] = es * inv;   // weight for supp branch
      s_scalar[4] = eq * inv;   // weight for query branch
    }
  }
  __syncthreads();

  // ---- per-row weight + channel partial sums ----
  {
    const float wsup = s_scalar[3], wqry = s_scalar[4];
    const int n = tid;
    float wn = (s_dot[n] >= 0.0f) ? wsup : wqry;
    w_out[bc * Nn + n] = wn;
    float ps  = wn * s_rs[n];
    float pss = wn * wn * s_rss[n];
#pragma unroll
    for (int off = 32; off >= 1; off >>= 1) {
      ps  += __shfl_xor(ps, off, 64);
      pss += __shfl_xor(pss, off, 64);
    }
    if (lane == 0) { s_wp[wv] = ps; s_wp[4 + wv] = pss; }
  }
  __syncthreads();
  if (tid == 0) {
    float S  = s_wp[0] + s_wp[1] + s_wp[2] + s_wp[3];
    float SS = s_wp[4] + s_wp[5] + s_wp[6] + s_wp[7];
    partials[bc * 2]     = S;
    partials[bc * 2 + 1] = SS;
  }
}

// ---------------------------------------------------------------------------
// k2: finalize per-channel BN stats, then elementwise elu((h*w)*scale + shift)
// ---------------------------------------------------------------------------
__global__ __launch_bounds__(256) void k2(
    const float* __restrict__ h, const float* __restrict__ w_in,
    const float* __restrict__ partials, const float* __restrict__ gamma,
    const float* __restrict__ beta, float* __restrict__ out) {
  const int bc = blockIdx.x;
  const int c = bc & (Cc - 1);
  const int tid = threadIdx.x;
  __shared__ float s_w[Nn];
  __shared__ float s_sc[2];

  s_w[tid] = w_in[bc * Nn + tid];
  if (tid == 0) {
    float S = 0.0f, SS = 0.0f;
#pragma unroll
    for (int b2 = 0; b2 < Bb; ++b2) {
      S  += partials[(b2 * Cc + c) * 2];
      SS += partials[(b2 * Cc + c) * 2 + 1];
    }
    const float invcnt = 1.0f / (float)(Bb * Nn * FD);
    float mean = S * invcnt;
    float var  = SS * invcnt - mean * mean;
    float inv  = rsqrtf(var + 1e-5f);
    float g = gamma[c] * inv;
    s_sc[0] = g;
    s_sc[1] = beta[c] - mean * g;
  }
  __syncthreads();

  const float scale = s_sc[0], shift = s_sc[1];
  const float4* __restrict__ h4 = (const float4*)(h + (size_t)bc * (Nn * FD));
  float4* __restrict__ o4 = (float4*)(out + (size_t)bc * (Nn * FD));
#pragma unroll 4
  for (int i = tid; i < Nn * FD / 4; i += 256) {
    const float wn = s_w[i >> 5];   // 32 float4 per row
    float4 v = h4[i];
    float4 r;
    r.x = v.x * wn * scale + shift;
    r.y = v.y * wn * scale + shift;
    r.z = v.z * wn * scale + shift;
    r.w = v.w * wn * scale + shift;
    r.x = (r.x > 0.0f) ? r.x : expm1f(r.x);
    r.y = (r.y > 0.0f) ? r.y : expm1f(r.y);
    r.z = (r.z > 0.0f) ? r.z : expm1f(r.z);
    r.w = (r.w > 0.0f) ? r.w : expm1f(r.w);
    o4[i] = r;
  }
}

extern "C" void kernel_launch(void* const* d_in, const int* in_sizes, int n_in,
                              void* d_out, int out_size, void* d_ws, size_t ws_size,
                              hipStream_t stream) {
  const float* h     = (const float*)d_in[0];
  const float* op    = (const float*)d_in[1];
  const float* opS   = (const float*)d_in[2];
  const float* opQ   = (const float*)d_in[3];
  const float* gamma = (const float*)d_in[4];
  const float* beta  = (const float*)d_in[5];
  float* out = (float*)d_out;

  float* w_ws     = (float*)d_ws;                 // Bb*Cc*Nn floats (512 KiB)
  float* partials = w_ws + Bb * Cc * Nn;          // Bb*Cc*2 floats

  k1<<<Bb * Cc, 256, 0, stream>>>(h, op, opS, opQ, w_ws, partials);
  k2<<<Bb * Cc, 256, 0, stream>>>(h, w_ws, partials, gamma, beta, out);
}

// Round 2
// 144.303 us; speedup vs baseline: 1.1092x; 1.1092x over previous
//
#include <hip/hip_runtime.h>
#include <math.h>

#define Bb 8
#define Cc 64
#define Nn 256
#define FD 128
#define SEGS 4
#define ROWS 64          // rows per s1/s3 block
#define TILE (Nn * FD)   // 32768 floats per (b,c)

// ---------------------------------------------------------------------------
// s1: one block per (bc, seg) — 64 rows. Single pass over its 32 KB slice.
// Per row: dotH (mask logit, h-half of op), dotS (h·opS[:FD]), dotQ,
// rowsum, rowsumsq. Then mask = dotH+const_src >= 0 (ballot -> u64),
// and 6 masked block partials: [Σm dotS, Σq dotQ, Σm rs, Σq rs, Σm rss, Σq rss].
// ---------------------------------------------------------------------------
__global__ __launch_bounds__(256) void s1(
    const float* __restrict__ h, const float* __restrict__ op,
    const float* __restrict__ opS, const float* __restrict__ opQ,
    unsigned long long* __restrict__ maskbuf, float* __restrict__ bpart) {
  const int blk = blockIdx.x;
  const int bc = blk >> 2, seg = blk & 3;
  const int c = bc & (Cc - 1);
  const float* __restrict__ tile = h + (size_t)bc * TILE;
  const int tid = threadIdx.x, lane = tid & 63, wv = tid >> 6;
  const int hw = tid >> 5, hl = tid & 31;

  __shared__ float s_dh[ROWS], s_dS[ROWS], s_dQ[ROWS], s_rs[ROWS], s_rss[ROWS];

  // wave 0: const_src = <source_row, op[c][0:FD]> (full butterfly -> all lanes)
  float const_src = 0.0f;
  if (wv == 0) {
    const float* __restrict__ opc = op + c * 2 * FD;
    float a = tile[lane], b = tile[lane + 64];
    float cs = a * opc[lane] + b * opc[lane + 64];
#pragma unroll
    for (int off = 32; off >= 1; off >>= 1) cs += __shfl_xor(cs, off, 64);
    const_src = cs;
  }

  const float4 oH = ((const float4*)(op  + c * 2 * FD + FD))[hl];
  const float4 oS = ((const float4*)(opS + c * 2 * FD))[hl];
  const float4 oQ = ((const float4*)(opQ + c * 2 * FD))[hl];

  // 8 half-waves x 8 rows = 64 rows; each half-wave lane loads one float4/row
#pragma unroll
  for (int i = 0; i < 8; ++i) {
    const int nl = hw * 8 + i;
    const float4 v = ((const float4*)(tile + (size_t)(seg * ROWS + nl) * FD))[hl];
    float dh  = v.x * oH.x + v.y * oH.y + v.z * oH.z + v.w * oH.w;
    float ds  = v.x * oS.x + v.y * oS.y + v.z * oS.z + v.w * oS.w;
    float dq  = v.x * oQ.x + v.y * oQ.y + v.z * oQ.z + v.w * oQ.w;
    float rs  = v.x + v.y + v.z + v.w;
    float rss = v.x * v.x + v.y * v.y + v.z * v.z + v.w * v.w;
#pragma unroll
    for (int off = 16; off >= 1; off >>= 1) {
      dh  += __shfl_xor(dh,  off, 64);
      ds  += __shfl_xor(ds,  off, 64);
      dq  += __shfl_xor(dq,  off, 64);
      rs  += __shfl_xor(rs,  off, 64);
      rss += __shfl_xor(rss, off, 64);
    }
    if (hl == 0) {
      s_dh[nl] = dh; s_dS[nl] = ds; s_dQ[nl] = dq; s_rs[nl] = rs; s_rss[nl] = rss;
    }
  }
  __syncthreads();

  if (wv == 0) {
    const int r = lane;
    const bool m = (s_dh[r] + const_src) >= 0.0f;
    const unsigned long long bits = __ballot(m);
    float dsm  = m ? s_dS[r]  : 0.0f;
    float dqq  = m ? 0.0f     : s_dQ[r];
    float rsm  = m ? s_rs[r]  : 0.0f;
    float rsq  = m ? 0.0f     : s_rs[r];
    float rssm = m ? s_rss[r] : 0.0f;
    float rssq = m ? 0.0f     : s_rss[r];
#pragma unroll
    for (int off = 32; off >= 1; off >>= 1) {
      dsm  += __shfl_xor(dsm,  off, 64);
      dqq  += __shfl_xor(dqq,  off, 64);
      rsm  += __shfl_xor(rsm,  off, 64);
      rsq  += __shfl_xor(rsq,  off, 64);
      rssm += __shfl_xor(rssm, off, 64);
      rssq += __shfl_xor(rssq, off, 64);
    }
    if (lane == 0) {
      float* p = bpart + blk * 8;
      p[0] = dsm; p[1] = dqq; p[2] = rsm; p[3] = rsq; p[4] = rssm; p[5] = rssq;
      maskbuf[blk] = bits;
    }
  }
}

// ---------------------------------------------------------------------------
// s2: one block per channel c. Source dots (opS/opQ source halves), combine
// the 4 seg-partials per (b,c) -> softmax (w_s,w_q), accumulate channel
// BN sums over b -> scale/shift.
// ---------------------------------------------------------------------------
__global__ __launch_bounds__(256) void s2(
    const float* __restrict__ h, const float* __restrict__ opS,
    const float* __restrict__ opQ, const float* __restrict__ bpart,
    const float* __restrict__ gamma, const float* __restrict__ beta,
    float* __restrict__ wsq, float* __restrict__ chan) {
  const int c = blockIdx.x;
  const int tid = threadIdx.x, lane = tid & 63, wv = tid >> 6, hl = tid & 31;
  const int b = wv * 2 + ((lane >> 5) & 1);
  __shared__ float s_S[Bb], s_SS[Bb];

  const int bc = b * Cc + c;
  const float4 s4 = ((const float4*)(h + (size_t)bc * TILE))[hl];  // source row
  const float4 oS = ((const float4*)(opS + c * 2 * FD + FD))[hl];
  const float4 oQ = ((const float4*)(opQ + c * 2 * FD + FD))[hl];
  float ss = s4.x * oS.x + s4.y * oS.y + s4.z * oS.z + s4.w * oS.w;
  float qq = s4.x * oQ.x + s4.y * oQ.y + s4.z * oQ.z + s4.w * oQ.w;
#pragma unroll
  for (int off = 16; off >= 1; off >>= 1) {
    ss += __shfl_xor(ss, off, 64);
    qq += __shfl_xor(qq, off, 64);
  }

  if (hl == 0) {
    float a0 = 0, a1 = 0, a2 = 0, a3 = 0, a4 = 0, a5 = 0;
#pragma unroll
    for (int k = 0; k < SEGS; ++k) {
      const float* p = bpart + (size_t)(bc * SEGS + k) * 8;
      a0 += p[0]; a1 += p[1]; a2 += p[2]; a3 += p[3]; a4 += p[4]; a5 += p[5];
    }
    float sa = a0 * (1.0f / Nn) + ss;
    float qa = a1 * (1.0f / Nn) + qq;
    float mx = fmaxf(sa, qa);
    float es = __expf(sa - mx), eq = __expf(qa - mx);
    float inv = 1.0f / (es + eq);
    float w_s = es * inv, w_q = eq * inv;
    wsq[bc * 2] = w_s;
    wsq[bc * 2 + 1] = w_q;
    s_S[b]  = w_s * a2 + w_q * a3;
    s_SS[b] = w_s * w_s * a4 + w_q * w_q * a5;
  }
  __syncthreads();
  if (tid == 0) {
    float S = 0, SS = 0;
#pragma unroll
    for (int k = 0; k < Bb; ++k) { S += s_S[k]; SS += s_SS[k]; }
    const float invcnt = 1.0f / (float)(Bb * Nn * FD);
    float mean = S * invcnt;
    float var = SS * invcnt - mean * mean;
    float sc = gamma[c] * rsqrtf(var + 1e-5f);
    chan[c * 2] = sc;
    chan[c * 2 + 1] = beta[c] - mean * sc;
  }
}

// ---------------------------------------------------------------------------
// s3: one block per (bc, seg) — elementwise elu(fma(h, w*scale, shift))
// ---------------------------------------------------------------------------
__global__ __launch_bounds__(256) void s3(
    const float* __restrict__ h, const unsigned long long* __restrict__ maskbuf,
    const float* __restrict__ wsq, const float* __restrict__ chan,
    float* __restrict__ out) {
  const int blk = blockIdx.x, bc = blk >> 2, seg = blk & 3, c = bc & (Cc - 1);
  const int tid = threadIdx.x;
  __shared__ float s_a[ROWS];
  __shared__ float s_shift;
  if (tid < ROWS) {
    const unsigned long long m = maskbuf[blk];
    const float w = ((m >> tid) & 1ull) ? wsq[bc * 2] : wsq[bc * 2 + 1];
    s_a[tid] = w * chan[c * 2];
    if (tid == 0) s_shift = chan[c * 2 + 1];
  }
  __syncthreads();
  const float shift = s_shift;
  const float4* __restrict__ h4 = (const float4*)(h + (size_t)bc * TILE) + seg * 2048;
  float4* __restrict__ o4 = (float4*)(out + (size_t)bc * TILE) + seg * 2048;
#pragma unroll
  for (int k = 0; k < 8; ++k) {
    const int idx = k * 256 + tid;
    const float a = s_a[idx >> 5];   // 32 float4 per row
    float4 v = h4[idx];
    float4 r;
    r.x = fmaf(v.x, a, shift);
    r.y = fmaf(v.y, a, shift);
    r.z = fmaf(v.z, a, shift);
    r.w = fmaf(v.w, a, shift);
    r.x = r.x > 0.0f ? r.x : __expf(r.x) - 1.0f;
    r.y = r.y > 0.0f ? r.y : __expf(r.y) - 1.0f;
    r.z = r.z > 0.0f ? r.z : __expf(r.z) - 1.0f;
    r.w = r.w > 0.0f ? r.w : __expf(r.w) - 1.0f;
    o4[idx] = r;
  }
}

extern "C" void kernel_launch(void* const* d_in, const int* in_sizes, int n_in,
                              void* d_out, int out_size, void* d_ws, size_t ws_size,
                              hipStream_t stream) {
  const float* h     = (const float*)d_in[0];
  const float* op    = (const float*)d_in[1];
  const float* opS   = (const float*)d_in[2];
  const float* opQ   = (const float*)d_in[3];
  const float* gamma = (const float*)d_in[4];
  const float* beta  = (const float*)d_in[5];
  float* out = (float*)d_out;

  // ws layout
  unsigned long long* maskbuf = (unsigned long long*)d_ws;           // 2048 u64 = 16 KB
  float* bpart = (float*)((char*)d_ws + 16384);                      // 2048*8 fl = 64 KB
  float* wsq   = (float*)((char*)d_ws + 16384 + 65536);              // 1024 fl  = 4 KB
  float* chan  = (float*)((char*)d_ws + 16384 + 65536 + 4096);       // 128 fl

  s1<<<Bb * Cc * SEGS, 256, 0, stream>>>(h, op, opS, opQ, maskbuf, bpart);
  s2<<<Cc, 256, 0, stream>>>(h, opS, opQ, bpart, gamma, beta, wsq, chan);
  s3<<<Bb * Cc * SEGS, 256, 0, stream>>>(h, maskbuf, wsq, chan, out);
}

// Round 3
// 142.097 us; speedup vs baseline: 1.1264x; 1.0155x over previous
//
#include <hip/hip_runtime.h>
#include <math.h>

#define Bb 8
#define Cc 64
#define Nn 256
#define FD 128
#define SEGS 4
#define ROWS 64          // rows per block
#define TILE (Nn * FD)   // 32768 floats per (b,c)

// ---------------------------------------------------------------------------
// s1: one block per (bc, seg) — 64 rows, single pass over its 32 KB slice.
// Per row: dotH (mask logit), dotS, dotQ, rowsum, rowsumsq.
// Emits: 64-bit row mask + 6 masked block partials
//   [Σm dotS, Σq dotQ, Σm rs, Σq rs, Σm rss, Σq rss]
// ---------------------------------------------------------------------------
__global__ __launch_bounds__(256) void s1(
    const float* __restrict__ h, const float* __restrict__ op,
    const float* __restrict__ opS, const float* __restrict__ opQ,
    unsigned long long* __restrict__ maskbuf, float* __restrict__ bpart) {
  const int blk = blockIdx.x;
  const int bc = blk >> 2, seg = blk & 3;
  const int c = bc & (Cc - 1);
  const float* __restrict__ tile = h + (size_t)bc * TILE;
  const int tid = threadIdx.x, lane = tid & 63, wv = tid >> 6;
  const int hw = tid >> 5, hl = tid & 31;

  __shared__ float s_dh[ROWS], s_dS[ROWS], s_dQ[ROWS], s_rs[ROWS], s_rss[ROWS];

  // wave 0: const_src = <source_row, op[c][0:FD]>
  float const_src = 0.0f;
  if (wv == 0) {
    const float* __restrict__ opc = op + c * 2 * FD;
    float a = tile[lane], b = tile[lane + 64];
    float cs = a * opc[lane] + b * opc[lane + 64];
#pragma unroll
    for (int off = 32; off >= 1; off >>= 1) cs += __shfl_xor(cs, off, 64);
    const_src = cs;
  }

  const float4 oH = ((const float4*)(op  + c * 2 * FD + FD))[hl];
  const float4 oS = ((const float4*)(opS + c * 2 * FD))[hl];
  const float4 oQ = ((const float4*)(opQ + c * 2 * FD))[hl];

  // 8 half-waves x 8 rows = 64 rows; one float4 per half-wave-lane per row
#pragma unroll
  for (int i = 0; i < 8; ++i) {
    const int nl = hw * 8 + i;
    const float4 v = ((const float4*)(tile + (size_t)(seg * ROWS + nl) * FD))[hl];
    float dh  = v.x * oH.x + v.y * oH.y + v.z * oH.z + v.w * oH.w;
    float ds  = v.x * oS.x + v.y * oS.y + v.z * oS.z + v.w * oS.w;
    float dq  = v.x * oQ.x + v.y * oQ.y + v.z * oQ.z + v.w * oQ.w;
    float rs  = v.x + v.y + v.z + v.w;
    float rss = v.x * v.x + v.y * v.y + v.z * v.z + v.w * v.w;
#pragma unroll
    for (int off = 16; off >= 1; off >>= 1) {
      dh  += __shfl_xor(dh,  off, 64);
      ds  += __shfl_xor(ds,  off, 64);
      dq  += __shfl_xor(dq,  off, 64);
      rs  += __shfl_xor(rs,  off, 64);
      rss += __shfl_xor(rss, off, 64);
    }
    if (hl == 0) {
      s_dh[nl] = dh; s_dS[nl] = ds; s_dQ[nl] = dq; s_rs[nl] = rs; s_rss[nl] = rss;
    }
  }
  __syncthreads();

  if (wv == 0) {
    const int r = lane;
    const bool m = (s_dh[r] + const_src) >= 0.0f;
    const unsigned long long bits = __ballot(m);
    float dsm  = m ? s_dS[r]  : 0.0f;
    float dqq  = m ? 0.0f     : s_dQ[r];
    float rsm  = m ? s_rs[r]  : 0.0f;
    float rsq  = m ? 0.0f     : s_rs[r];
    float rssm = m ? s_rss[r] : 0.0f;
    float rssq = m ? 0.0f     : s_rss[r];
#pragma unroll
    for (int off = 32; off >= 1; off >>= 1) {
      dsm  += __shfl_xor(dsm,  off, 64);
      dqq  += __shfl_xor(dqq,  off, 64);
      rsm  += __shfl_xor(rsm,  off, 64);
      rsq  += __shfl_xor(rsq,  off, 64);
      rssm += __shfl_xor(rssm, off, 64);
      rssq += __shfl_xor(rssq, off, 64);
    }
    if (lane == 0) {
      float* p = bpart + (size_t)blk * 8;
      p[0] = dsm; p[1] = dqq; p[2] = rsm; p[3] = rsq; p[4] = rssm; p[5] = rssq;
      maskbuf[blk] = bits;
    }
  }
}

// ---------------------------------------------------------------------------
// s2f: fused finalize + elementwise. One block per (bc, seg).
// Redundantly per block: for each b in 0..7 (one half-wave each): source dots
// (opS/opQ source halves), combine 4 seg-partials -> softmax (w_s,w_q),
// per-b BN contributions; then channel scale/shift; then
// elu(fma(h, w*scale, shift)) over the 32 KB slice.
// ---------------------------------------------------------------------------
__global__ __launch_bounds__(256) void s2f(
    const float* __restrict__ h, const unsigned long long* __restrict__ maskbuf,
    const float* __restrict__ bpart, const float* __restrict__ opS,
    const float* __restrict__ opQ, const float* __restrict__ gamma,
    const float* __restrict__ beta, float* __restrict__ out) {
  const int blk = blockIdx.x, bc = blk >> 2, seg = blk & 3;
  const int c = bc & (Cc - 1), bmine = bc >> 6;
  const int tid = threadIdx.x, lane = tid & 63, hw = tid >> 5, hl = tid & 31;
  __shared__ float s_S[Bb], s_SS[Bb], s_ws[2 * Bb];
  __shared__ float s_a[ROWS];

  const int b = hw;                    // 8 half-waves -> 8 batch entries
  const int bcb = b * Cc + c;

  // source dots for (b,c)
  const float4 s4 = ((const float4*)(h + (size_t)bcb * TILE))[hl];
  const float4 oS = ((const float4*)(opS + c * 2 * FD + FD))[hl];
  const float4 oQ = ((const float4*)(opQ + c * 2 * FD + FD))[hl];
  float ss = s4.x * oS.x + s4.y * oS.y + s4.z * oS.z + s4.w * oS.w;
  float qq = s4.x * oQ.x + s4.y * oQ.y + s4.z * oQ.z + s4.w * oQ.w;
#pragma unroll
  for (int off = 16; off >= 1; off >>= 1) {   // stays within half-wave
    ss += __shfl_xor(ss, off, 64);
    qq += __shfl_xor(qq, off, 64);
  }

  // combine the 4 seg-partials (lanes hl<6, one j each)
  float aj = 0.0f;
  if (hl < 6) {
#pragma unroll
    for (int k = 0; k < SEGS; ++k)
      aj += bpart[(size_t)(bcb * SEGS + k) * 8 + hl];
  }
  const int base = lane & 32;
  float a0 = __shfl(aj, base + 0, 64), a1 = __shfl(aj, base + 1, 64);
  float a2 = __shfl(aj, base + 2, 64), a3 = __shfl(aj, base + 3, 64);
  float a4 = __shfl(aj, base + 4, 64), a5 = __shfl(aj, base + 5, 64);

  float sa = a0 * (1.0f / Nn) + ss;
  float qa = a1 * (1.0f / Nn) + qq;
  float mx = fmaxf(sa, qa);
  float es = __expf(sa - mx), eq = __expf(qa - mx);
  float inv = 1.0f / (es + eq);
  float w_s = es * inv, w_q = eq * inv;
  if (hl == 0) {
    s_S[b]  = w_s * a2 + w_q * a3;
    s_SS[b] = w_s * w_s * a4 + w_q * w_q * a5;
    s_ws[2 * b] = w_s; s_ws[2 * b + 1] = w_q;
  }
  __syncthreads();

  // channel stats (all threads redundantly, LDS broadcast reads)
  float S = 0.0f, SS = 0.0f;
#pragma unroll
  for (int k = 0; k < Bb; ++k) { S += s_S[k]; SS += s_SS[k]; }
  const float invcnt = 1.0f / (float)(Bb * Nn * FD);
  const float mean = S * invcnt;
  const float var  = SS * invcnt - mean * mean;
  const float scale = gamma[c] * rsqrtf(var + 1e-5f);
  const float shift = beta[c] - mean * scale;

  if (tid < ROWS) {
    const unsigned long long m = maskbuf[blk];
    const float w = ((m >> tid) & 1ull) ? s_ws[2 * bmine] : s_ws[2 * bmine + 1];
    s_a[tid] = w * scale;
  }
  __syncthreads();

  const float4* __restrict__ h4 = (const float4*)(h + (size_t)bc * TILE) + seg * 2048;
  float4* __restrict__ o4 = (float4*)(out + (size_t)bc * TILE) + seg * 2048;
#pragma unroll
  for (int k = 0; k < 8; ++k) {
    const int idx = k * 256 + tid;
    const float a = s_a[idx >> 5];   // 32 float4 per row -> broadcast per 32 lanes
    float4 v = h4[idx];
    float4 r;
    r.x = fmaf(v.x, a, shift);
    r.y = fmaf(v.y, a, shift);
    r.z = fmaf(v.z, a, shift);
    r.w = fmaf(v.w, a, shift);
    r.x = r.x > 0.0f ? r.x : __expf(r.x) - 1.0f;
    r.y = r.y > 0.0f ? r.y : __expf(r.y) - 1.0f;
    r.z = r.z > 0.0f ? r.z : __expf(r.z) - 1.0f;
    r.w = r.w > 0.0f ? r.w : __expf(r.w) - 1.0f;
    o4[idx] = r;
  }
}

extern "C" void kernel_launch(void* const* d_in, const int* in_sizes, int n_in,
                              void* d_out, int out_size, void* d_ws, size_t ws_size,
                              hipStream_t stream) {
  const float* h     = (const float*)d_in[0];
  const float* op    = (const float*)d_in[1];
  const float* opS   = (const float*)d_in[2];
  const float* opQ   = (const float*)d_in[3];
  const float* gamma = (const float*)d_in[4];
  const float* beta  = (const float*)d_in[5];
  float* out = (float*)d_out;

  unsigned long long* maskbuf = (unsigned long long*)d_ws;   // 2048 u64 = 16 KB
  float* bpart = (float*)((char*)d_ws + 16384);              // 2048*8 floats = 64 KB

  s1<<<Bb * Cc * SEGS, 256, 0, stream>>>(h, op, opS, opQ, maskbuf, bpart);
  s2f<<<Bb * Cc * SEGS, 256, 0, stream>>>(h, maskbuf, bpart, opS, opQ, gamma, beta, out);
}

// Round 6
// 140.796 us; speedup vs baseline: 1.1368x; 1.0092x over previous
//
#include <hip/hip_runtime.h>
#include <math.h>

#define Bb 8
#define Cc 64
#define Nn 256
#define FD 128
#define SEGS 4
#define ROWS 64          // rows per block
#define TILE (Nn * FD)   // 32768 floats per (b,c)

typedef float floatx4 __attribute__((ext_vector_type(4)));

// ---------------------------------------------------------------------------
// s1: one block per (bc, seg) — 64 rows, single pass over its 32 KB slice.
// Per row: dotH (mask logit), dotS, dotQ, rowsum, rowsumsq.
// Emits: 64-bit row mask + 6 masked block partials
//   [Σm dotS, Σq dotQ, Σm rs, Σq rs, Σm rss, Σq rss]
// ---------------------------------------------------------------------------
__global__ __launch_bounds__(256) void s1(
    const float* __restrict__ h, const float* __restrict__ op,
    const float* __restrict__ opS, const float* __restrict__ opQ,
    unsigned long long* __restrict__ maskbuf, float* __restrict__ bpart) {
  const int blk = blockIdx.x;
  const int bc = blk >> 2, seg = blk & 3;
  const int c = bc & (Cc - 1);
  const float* __restrict__ tile = h + (size_t)bc * TILE;
  const int tid = threadIdx.x, lane = tid & 63, wv = tid >> 6;
  const int hw = tid >> 5, hl = tid & 31;

  __shared__ float s_dh[ROWS], s_dS[ROWS], s_dQ[ROWS], s_rs[ROWS], s_rss[ROWS];

  // wave 0: const_src = <source_row, op[c][0:FD]>
  float const_src = 0.0f;
  if (wv == 0) {
    const float* __restrict__ opc = op + c * 2 * FD;
    float a = tile[lane], b = tile[lane + 64];
    float cs = a * opc[lane] + b * opc[lane + 64];
#pragma unroll
    for (int off = 32; off >= 1; off >>= 1) cs += __shfl_xor(cs, off, 64);
    const_src = cs;
  }

  const float4 oH = ((const float4*)(op  + c * 2 * FD + FD))[hl];
  const float4 oS = ((const float4*)(opS + c * 2 * FD))[hl];
  const float4 oQ = ((const float4*)(opQ + c * 2 * FD))[hl];

  // 8 half-waves x 8 rows = 64 rows; one float4 per half-wave-lane per row
#pragma unroll
  for (int i = 0; i < 8; ++i) {
    const int nl = hw * 8 + i;
    const float4 v = ((const float4*)(tile + (size_t)(seg * ROWS + nl) * FD))[hl];
    float dh  = v.x * oH.x + v.y * oH.y + v.z * oH.z + v.w * oH.w;
    float ds  = v.x * oS.x + v.y * oS.y + v.z * oS.z + v.w * oS.w;
    float dq  = v.x * oQ.x + v.y * oQ.y + v.z * oQ.z + v.w * oQ.w;
    float rs  = v.x + v.y + v.z + v.w;
    float rss = v.x * v.x + v.y * v.y + v.z * v.z + v.w * v.w;
#pragma unroll
    for (int off = 16; off >= 1; off >>= 1) {
      dh  += __shfl_xor(dh,  off, 64);
      ds  += __shfl_xor(ds,  off, 64);
      dq  += __shfl_xor(dq,  off, 64);
      rs  += __shfl_xor(rs,  off, 64);
      rss += __shfl_xor(rss, off, 64);
    }
    if (hl == 0) {
      s_dh[nl] = dh; s_dS[nl] = ds; s_dQ[nl] = dq; s_rs[nl] = rs; s_rss[nl] = rss;
    }
  }
  __syncthreads();

  if (wv == 0) {
    const int r = lane;
    const bool m = (s_dh[r] + const_src) >= 0.0f;
    const unsigned long long bits = __ballot(m);
    float dsm  = m ? s_dS[r]  : 0.0f;
    float dqq  = m ? 0.0f     : s_dQ[r];
    float rsm  = m ? s_rs[r]  : 0.0f;
    float rsq  = m ? 0.0f     : s_rs[r];
    float rssm = m ? s_rss[r] : 0.0f;
    float rssq = m ? 0.0f     : s_rss[r];
#pragma unroll
    for (int off = 32; off >= 1; off >>= 1) {
      dsm  += __shfl_xor(dsm,  off, 64);
      dqq  += __shfl_xor(dqq,  off, 64);
      rsm  += __shfl_xor(rsm,  off, 64);
      rsq  += __shfl_xor(rsq,  off, 64);
      rssm += __shfl_xor(rssm, off, 64);
      rssq += __shfl_xor(rssq, off, 64);
    }
    if (lane == 0) {
      float* p = bpart + (size_t)blk * 8;
      p[0] = dsm; p[1] = dqq; p[2] = rsm; p[3] = rsq; p[4] = rssm; p[5] = rssq;
      maskbuf[blk] = bits;
    }
  }
}

// ---------------------------------------------------------------------------
// s2f: fused finalize + elementwise. One block per (bc, seg).
// Redundantly per block: per-b softmax weights + channel BN scale/shift,
// then elu(fma(h, w*scale, shift)) over the 32 KB slice (L3-hot re-read),
// nontemporal stores for the write-once output.
// ---------------------------------------------------------------------------
__global__ __launch_bounds__(256) void s2f(
    const float* __restrict__ h, const unsigned long long* __restrict__ maskbuf,
    const float* __restrict__ bpart, const float* __restrict__ opS,
    const float* __restrict__ opQ, const float* __restrict__ gamma,
    const float* __restrict__ beta, float* __restrict__ out) {
  const int blk = blockIdx.x, bc = blk >> 2, seg = blk & 3;
  const int c = bc & (Cc - 1), bmine = bc >> 6;
  const int tid = threadIdx.x, lane = tid & 63, hw = tid >> 5, hl = tid & 31;
  __shared__ float s_S[Bb], s_SS[Bb], s_ws[2 * Bb];
  __shared__ float s_a[ROWS];

  const int b = hw;                    // 8 half-waves -> 8 batch entries
  const int bcb = b * Cc + c;

  // source dots for (b,c)
  const float4 s4 = ((const float4*)(h + (size_t)bcb * TILE))[hl];
  const float4 oS = ((const float4*)(opS + c * 2 * FD + FD))[hl];
  const float4 oQ = ((const float4*)(opQ + c * 2 * FD + FD))[hl];
  float ss = s4.x * oS.x + s4.y * oS.y + s4.z * oS.z + s4.w * oS.w;
  float qq = s4.x * oQ.x + s4.y * oQ.y + s4.z * oQ.z + s4.w * oQ.w;
#pragma unroll
  for (int off = 16; off >= 1; off >>= 1) {   // stays within half-wave
    ss += __shfl_xor(ss, off, 64);
    qq += __shfl_xor(qq, off, 64);
  }

  // combine the 4 seg-partials (lanes hl<6, one j each)
  float aj = 0.0f;
  if (hl < 6) {
#pragma unroll
    for (int k = 0; k < SEGS; ++k)
      aj += bpart[(size_t)(bcb * SEGS + k) * 8 + hl];
  }
  const int base = lane & 32;
  float a0 = __shfl(aj, base + 0, 64), a1 = __shfl(aj, base + 1, 64);
  float a2 = __shfl(aj, base + 2, 64), a3 = __shfl(aj, base + 3, 64);
  float a4 = __shfl(aj, base + 4, 64), a5 = __shfl(aj, base + 5, 64);

  float sa = a0 * (1.0f / Nn) + ss;
  float qa = a1 * (1.0f / Nn) + qq;
  float mx = fmaxf(sa, qa);
  float es = __expf(sa - mx), eq = __expf(qa - mx);
  float inv = 1.0f / (es + eq);
  float w_s = es * inv, w_q = eq * inv;
  if (hl == 0) {
    s_S[b]  = w_s * a2 + w_q * a3;
    s_SS[b] = w_s * w_s * a4 + w_q * w_q * a5;
    s_ws[2 * b] = w_s; s_ws[2 * b + 1] = w_q;
  }
  __syncthreads();

  // channel stats (all threads redundantly, LDS broadcast reads)
  float S = 0.0f, SS = 0.0f;
#pragma unroll
  for (int k = 0; k < Bb; ++k) { S += s_S[k]; SS += s_SS[k]; }
  const float invcnt = 1.0f / (float)(Bb * Nn * FD);
  const float mean = S * invcnt;
  const float var  = SS * invcnt - mean * mean;
  const float scale = gamma[c] * rsqrtf(var + 1e-5f);
  const float shift = beta[c] - mean * scale;

  if (tid < ROWS) {
    const unsigned long long m = maskbuf[blk];
    const float w = ((m >> tid) & 1ull) ? s_ws[2 * bmine] : s_ws[2 * bmine + 1];
    s_a[tid] = w * scale;
  }
  __syncthreads();

  const float4* __restrict__ h4 = (const float4*)(h + (size_t)bc * TILE) + seg * 2048;
  floatx4* __restrict__ o4 = (floatx4*)(out + (size_t)bc * TILE) + seg * 2048;
#pragma unroll
  for (int k = 0; k < 8; ++k) {
    const int idx = k * 256 + tid;
    const float a = s_a[idx >> 5];   // 32 float4 per row -> broadcast per 32 lanes
    float4 v = h4[idx];
    floatx4 r;
    r.x = fmaf(v.x, a, shift);
    r.y = fmaf(v.y, a, shift);
    r.z = fmaf(v.z, a, shift);
    r.w = fmaf(v.w, a, shift);
    r.x = r.x > 0.0f ? r.x : __expf(r.x) - 1.0f;
    r.y = r.y > 0.0f ? r.y : __expf(r.y) - 1.0f;
    r.z = r.z > 0.0f ? r.z : __expf(r.z) - 1.0f;
    r.w = r.w > 0.0f ? r.w : __expf(r.w) - 1.0f;
    __builtin_nontemporal_store(r, &o4[idx]);
  }
}

extern "C" void kernel_launch(void* const* d_in, const int* in_sizes, int n_in,
                              void* d_out, int out_size, void* d_ws, size_t ws_size,
                              hipStream_t stream) {
  const float* h     = (const float*)d_in[0];
  const float* op    = (const float*)d_in[1];
  const float* opS   = (const float*)d_in[2];
  const float* opQ   = (const float*)d_in[3];
  const float* gamma = (const float*)d_in[4];
  const float* beta  = (const float*)d_in[5];
  float* out = (float*)d_out;

  unsigned long long* maskbuf = (unsigned long long*)d_ws;   // 2048 u64 = 16 KB
  float* bpart = (float*)((char*)d_ws + 16384);              // 2048*8 floats = 64 KB

  s1<<<Bb * Cc * SEGS, 256, 0, stream>>>(h, op, opS, opQ, maskbuf, bpart);
  s2f<<<Bb * Cc * SEGS, 256, 0, stream>>>(h, maskbuf, bpart, opS, opQ, gamma, beta, out);
}

// Round 7
// 133.829 us; speedup vs baseline: 1.1960x; 1.0521x over previous
//
#include <hip/hip_runtime.h>
#include <math.h>

#define Bb 8
#define Cc 64
#define Nn 256
#define FD 128
#define SEGS 4
#define ROWS 64          // rows per block
#define TILE (Nn * FD)   // 32768 floats per (b,c)

typedef float floatx4 __attribute__((ext_vector_type(4)));

// ---------------------------------------------------------------------------
// s1: one block per (bc, seg) — 64 rows, single pass over its 32 KB slice.
// Only the mask logit dh is reduced per-row; dotS/dotQ/rowsum/rowsumsq are
// kept as per-lane register partials and folded with the mask AFTER the
// barrier, then reduced once block-wide (6 values).
// Emits: 64-bit row mask + 6 masked block partials
//   [Σm dotS, Σq dotQ, Σm rs, Σq rs, Σm rss, Σq rss]
// ---------------------------------------------------------------------------
__global__ __launch_bounds__(256) void s1(
    const float* __restrict__ h, const float* __restrict__ op,
    const float* __restrict__ opS, const float* __restrict__ opQ,
    unsigned long long* __restrict__ maskbuf, float* __restrict__ bpart) {
  const int blk = blockIdx.x;
  const int bc = blk >> 2, seg = blk & 3;
  const int c = bc & (Cc - 1);
  const float* __restrict__ tile = h + (size_t)bc * TILE;
  const int tid = threadIdx.x, lane = tid & 63, wv = tid >> 6;
  const int hw = tid >> 5, hl = tid & 31;

  __shared__ float s_dh[ROWS];
  __shared__ float s_red[4][6];
  __shared__ float s_cs;

  // wave 0: const_src = <source_row, op[c][0:FD]> -> LDS for all waves
  if (wv == 0) {
    const float* __restrict__ opc = op + c * 2 * FD;
    float a = tile[lane], b = tile[lane + 64];
    float cs = a * opc[lane] + b * opc[lane + 64];
#pragma unroll
    for (int off = 32; off >= 1; off >>= 1) cs += __shfl_xor(cs, off, 64);
    if (lane == 0) s_cs = cs;
  }

  const float4 oH = ((const float4*)(op  + c * 2 * FD + FD))[hl];
  const float4 oS = ((const float4*)(opS + c * 2 * FD))[hl];
  const float4 oQ = ((const float4*)(opQ + c * 2 * FD))[hl];

  float dsp[8], dqp[8], rsp[8], rssp[8];

  // 8 half-waves x 8 rows = 64 rows; one float4 per half-wave-lane per row.
  // Per iteration only dh is butterfly-reduced (5 steps, both halves).
#pragma unroll
  for (int i = 0; i < 8; ++i) {
    const int nl = hw * 8 + i;
    const float4 v = ((const float4*)(tile + (size_t)(seg * ROWS + nl) * FD))[hl];
    float dh = v.x * oH.x + v.y * oH.y + v.z * oH.z + v.w * oH.w;
    dsp[i]  = v.x * oS.x + v.y * oS.y + v.z * oS.z + v.w * oS.w;
    dqp[i]  = v.x * oQ.x + v.y * oQ.y + v.z * oQ.z + v.w * oQ.w;
    rsp[i]  = v.x + v.y + v.z + v.w;
    rssp[i] = v.x * v.x + v.y * v.y + v.z * v.z + v.w * v.w;
#pragma unroll
    for (int off = 16; off >= 1; off >>= 1) dh += __shfl_xor(dh, off, 64);
    if (hl == 0) s_dh[nl] = dh;
  }
  __syncthreads();

  const float cs = s_cs;

  // ballot mask (wave 0 handles all 64 rows)
  if (wv == 0) {
    const bool m = (s_dh[lane] + cs) >= 0.0f;
    const unsigned long long bits = __ballot(m);
    if (lane == 0) maskbuf[blk] = bits;
  }

  // mask-weighted lane-local accumulation over this lane's 8 rows
  float a_ds = 0, a_dq = 0, a_rsm = 0, a_rsq = 0, a_rssm = 0, a_rssq = 0;
#pragma unroll
  for (int i = 0; i < 8; ++i) {
    const bool m = (s_dh[hw * 8 + i] + cs) >= 0.0f;
    a_ds   += m ? dsp[i]  : 0.0f;
    a_dq   += m ? 0.0f    : dqp[i];
    a_rsm  += m ? rsp[i]  : 0.0f;
    a_rsq  += m ? 0.0f    : rsp[i];
    a_rssm += m ? rssp[i] : 0.0f;
    a_rssq += m ? 0.0f    : rssp[i];
  }
  // one full-wave butterfly (6 steps x 6 values)
#pragma unroll
  for (int off = 32; off >= 1; off >>= 1) {
    a_ds   += __shfl_xor(a_ds,   off, 64);
    a_dq   += __shfl_xor(a_dq,   off, 64);
    a_rsm  += __shfl_xor(a_rsm,  off, 64);
    a_rsq  += __shfl_xor(a_rsq,  off, 64);
    a_rssm += __shfl_xor(a_rssm, off, 64);
    a_rssq += __shfl_xor(a_rssq, off, 64);
  }
  if (lane == 0) {
    s_red[wv][0] = a_ds;  s_red[wv][1] = a_dq;
    s_red[wv][2] = a_rsm; s_red[wv][3] = a_rsq;
    s_red[wv][4] = a_rssm; s_red[wv][5] = a_rssq;
  }
  __syncthreads();
  if (tid < 6) {
    bpart[(size_t)blk * 8 + tid] =
        s_red[0][tid] + s_red[1][tid] + s_red[2][tid] + s_red[3][tid];
  }
}

// ---------------------------------------------------------------------------
// s2f: fused finalize + elementwise. One block per (bc, seg).
// Redundantly per block: per-b softmax weights + channel BN scale/shift,
// then elu(fma(h, w*scale, shift)) over the 32 KB slice (L3-hot re-read),
// nontemporal stores for the write-once output.
// ---------------------------------------------------------------------------
__global__ __launch_bounds__(256) void s2f(
    const float* __restrict__ h, const unsigned long long* __restrict__ maskbuf,
    const float* __restrict__ bpart, const float* __restrict__ opS,
    const float* __restrict__ opQ, const float* __restrict__ gamma,
    const float* __restrict__ beta, float* __restrict__ out) {
  const int blk = blockIdx.x, bc = blk >> 2, seg = blk & 3;
  const int c = bc & (Cc - 1), bmine = bc >> 6;
  const int tid = threadIdx.x, lane = tid & 63, hw = tid >> 5, hl = tid & 31;
  __shared__ float s_S[Bb], s_SS[Bb], s_ws[2 * Bb];
  __shared__ float s_a[ROWS];

  const int b = hw;                    // 8 half-waves -> 8 batch entries
  const int bcb = b * Cc + c;

  // source dots for (b,c)
  const float4 s4 = ((const float4*)(h + (size_t)bcb * TILE))[hl];
  const float4 oS = ((const float4*)(opS + c * 2 * FD + FD))[hl];
  const float4 oQ = ((const float4*)(opQ + c * 2 * FD + FD))[hl];
  float ss = s4.x * oS.x + s4.y * oS.y + s4.z * oS.z + s4.w * oS.w;
  float qq = s4.x * oQ.x + s4.y * oQ.y + s4.z * oQ.z + s4.w * oQ.w;
#pragma unroll
  for (int off = 16; off >= 1; off >>= 1) {   // stays within half-wave
    ss += __shfl_xor(ss, off, 64);
    qq += __shfl_xor(qq, off, 64);
  }

  // combine the 4 seg-partials (lanes hl<6, one j each)
  float aj = 0.0f;
  if (hl < 6) {
#pragma unroll
    for (int k = 0; k < SEGS; ++k)
      aj += bpart[(size_t)(bcb * SEGS + k) * 8 + hl];
  }
  const int base = lane & 32;
  float a0 = __shfl(aj, base + 0, 64), a1 = __shfl(aj, base + 1, 64);
  float a2 = __shfl(aj, base + 2, 64), a3 = __shfl(aj, base + 3, 64);
  float a4 = __shfl(aj, base + 4, 64), a5 = __shfl(aj, base + 5, 64);

  float sa = a0 * (1.0f / Nn) + ss;
  float qa = a1 * (1.0f / Nn) + qq;
  float mx = fmaxf(sa, qa);
  float es = __expf(sa - mx), eq = __expf(qa - mx);
  float inv = 1.0f / (es + eq);
  float w_s = es * inv, w_q = eq * inv;
  if (hl == 0) {
    s_S[b]  = w_s * a2 + w_q * a3;
    s_SS[b] = w_s * w_s * a4 + w_q * w_q * a5;
    s_ws[2 * b] = w_s; s_ws[2 * b + 1] = w_q;
  }
  __syncthreads();

  // channel stats (all threads redundantly, LDS broadcast reads)
  float S = 0.0f, SS = 0.0f;
#pragma unroll
  for (int k = 0; k < Bb; ++k) { S += s_S[k]; SS += s_SS[k]; }
  const float invcnt = 1.0f / (float)(Bb * Nn * FD);
  const float mean = S * invcnt;
  const float var  = SS * invcnt - mean * mean;
  const float scale = gamma[c] * rsqrtf(var + 1e-5f);
  const float shift = beta[c] - mean * scale;

  if (tid < ROWS) {
    const unsigned long long m = maskbuf[blk];
    const float w = ((m >> tid) & 1ull) ? s_ws[2 * bmine] : s_ws[2 * bmine + 1];
    s_a[tid] = w * scale;
  }
  __syncthreads();

  const float4* __restrict__ h4 = (const float4*)(h + (size_t)bc * TILE) + seg * 2048;
  floatx4* __restrict__ o4 = (floatx4*)(out + (size_t)bc * TILE) + seg * 2048;
#pragma unroll
  for (int k = 0; k < 8; ++k) {
    const int idx = k * 256 + tid;
    const float a = s_a[idx >> 5];   // 32 float4 per row -> broadcast per 32 lanes
    float4 v = h4[idx];
    floatx4 r;
    r.x = fmaf(v.x, a, shift);
    r.y = fmaf(v.y, a, shift);
    r.z = fmaf(v.z, a, shift);
    r.w = fmaf(v.w, a, shift);
    r.x = r.x > 0.0f ? r.x : __expf(r.x) - 1.0f;
    r.y = r.y > 0.0f ? r.y : __expf(r.y) - 1.0f;
    r.z = r.z > 0.0f ? r.z : __expf(r.z) - 1.0f;
    r.w = r.w > 0.0f ? r.w : __expf(r.w) - 1.0f;
    __builtin_nontemporal_store(r, &o4[idx]);
  }
}

extern "C" void kernel_launch(void* const* d_in, const int* in_sizes, int n_in,
                              void* d_out, int out_size, void* d_ws, size_t ws_size,
                              hipStream_t stream) {
  const float* h     = (const float*)d_in[0];
  const float* op    = (const float*)d_in[1];
  const float* opS   = (const float*)d_in[2];
  const float* opQ   = (const float*)d_in[3];
  const float* gamma = (const float*)d_in[4];
  const float* beta  = (const float*)d_in[5];
  float* out = (float*)d_out;

  unsigned long long* maskbuf = (unsigned long long*)d_ws;   // 2048 u64 = 16 KB
  float* bpart = (float*)((char*)d_ws + 16384);              // 2048*8 floats = 64 KB

  s1<<<Bb * Cc * SEGS, 256, 0, stream>>>(h, op, opS, opQ, maskbuf, bpart);
  s2f<<<Bb * Cc * SEGS, 256, 0, stream>>>(h, maskbuf, bpart, opS, opQ, gamma, beta, out);
}